// Round 2
// baseline (2151.522 us; speedup 1.0000x reference)
//
#include <hip/hip_runtime.h>
#include <math.h>

// ---------------- problem constants ----------------
#define H 256
#define S_STEPS 4
#define B_RXN 512
#define N_MOLS 2048          // B*S
#define ATOMS_PER_MOL 32
#define N_ATOMS 65536        // N_MOLS*32
#define N_BONDS 131072
#define NBP1 131073          // N_BONDS+1
#define MAX_NB 6
#define ATOM_FDIM 133
#define BOND_FDIM 147
#define DEPTH 3
#define N_ITERS 3

typedef unsigned short bf16u;

__device__ __forceinline__ float b2f(bf16u u) {
    union { unsigned int i; float f; } c; c.i = ((unsigned int)u) << 16; return c.f;
}
__device__ __forceinline__ bf16u f2b(float f) {
    union { float f; unsigned int i; } c; c.f = f;
    unsigned int i = c.i;
    return (bf16u)((i + 0x7FFFu + ((i >> 16) & 1u)) >> 16);   // RNE
}

constexpr int BM = 64, BN = 64, BK = 16;

// ---------------- GEMM 1: inp = f_bonds @ W_i  (f32 x f32 -> bf16) ----------------
__global__ __launch_bounds__(256) void gemm_wi_k(
    const float* __restrict__ A,     // [NBP1, 147]
    const float* __restrict__ Bw,    // [147, 256]
    bf16u* __restrict__ C)           // [NBP1, 256] bf16
{
    __shared__ float As[BK][BM + 4];
    __shared__ float Bs[BK][BN];
    const int tid = threadIdx.x;
    const int m0 = blockIdx.y * BM, n0 = blockIdx.x * BN;
    const int tx = tid & 15, ty = tid >> 4;
    const int ar = tid >> 2, akq = (tid & 3) * 4;
    const int row = m0 + ar;
    const bool rowok = row < NBP1;
    float acc[4][4] = {};
    for (int k0 = 0; k0 < BOND_FDIM; k0 += BK) {
        #pragma unroll
        for (int j = 0; j < 4; ++j) {
            int kk = k0 + akq + j;
            As[akq + j][ar] = (rowok && kk < BOND_FDIM) ? A[(size_t)row * BOND_FDIM + kk] : 0.f;
        }
        const int bn = tid & 63, bk = tid >> 6;
        #pragma unroll
        for (int r = 0; r < 4; ++r) {
            int kk = k0 + bk + 4 * r;
            Bs[bk + 4 * r][bn] = (kk < BOND_FDIM) ? Bw[(size_t)kk * H + n0 + bn] : 0.f;
        }
        __syncthreads();
        #pragma unroll
        for (int kk = 0; kk < BK; ++kk) {
            float4 a = *(const float4*)&As[kk][ty * 4];
            float4 b = *(const float4*)&Bs[kk][tx * 4];
            acc[0][0] = fmaf(a.x, b.x, acc[0][0]); acc[0][1] = fmaf(a.x, b.y, acc[0][1]);
            acc[0][2] = fmaf(a.x, b.z, acc[0][2]); acc[0][3] = fmaf(a.x, b.w, acc[0][3]);
            acc[1][0] = fmaf(a.y, b.x, acc[1][0]); acc[1][1] = fmaf(a.y, b.y, acc[1][1]);
            acc[1][2] = fmaf(a.y, b.z, acc[1][2]); acc[1][3] = fmaf(a.y, b.w, acc[1][3]);
            acc[2][0] = fmaf(a.z, b.x, acc[2][0]); acc[2][1] = fmaf(a.z, b.y, acc[2][1]);
            acc[2][2] = fmaf(a.z, b.z, acc[2][2]); acc[2][3] = fmaf(a.z, b.w, acc[2][3]);
            acc[3][0] = fmaf(a.w, b.x, acc[3][0]); acc[3][1] = fmaf(a.w, b.y, acc[3][1]);
            acc[3][2] = fmaf(a.w, b.z, acc[3][2]); acc[3][3] = fmaf(a.w, b.w, acc[3][3]);
        }
        __syncthreads();
    }
    #pragma unroll
    for (int i = 0; i < 4; ++i) {
        int rr = m0 + ty * 4 + i;
        if (rr >= NBP1) continue;
        size_t off = (size_t)rr * H + n0 + tx * 4;
        ushort4 r;
        r.x = f2b(acc[i][0]); r.y = f2b(acc[i][1]);
        r.z = f2b(acc[i][2]); r.w = f2b(acc[i][3]);
        *(ushort4*)(C + off) = r;
    }
}

// ---------------- GEMM 2 (hot): next = relu(inp + (amsg[b2a]-msg[b2revb]) @ W_h) ----------------
__global__ __launch_bounds__(256) void gemm_msg_k(
    const bf16u* __restrict__ amsg,  // [N_ATOMS, 256] bf16
    const bf16u* __restrict__ msg,   // [NBP1, 256] bf16
    const bf16u* __restrict__ inp,   // [NBP1, 256] bf16
    const float* __restrict__ Wh,    // [256, 256]
    const int* __restrict__ b2a,
    const int* __restrict__ b2revb,
    bf16u* __restrict__ outm)        // [NBP1, 256] bf16
{
    __shared__ float As[BK][BM + 4];
    __shared__ float Bs[BK][BN];
    const int tid = threadIdx.x;
    const int m0 = blockIdx.y * BM, n0 = blockIdx.x * BN;
    const int tx = tid & 15, ty = tid >> 4;
    const int ar = tid >> 2, akq = (tid & 3) * 4;
    const int row = m0 + ar;
    const bool rowok = row < NBP1;
    size_t o1 = 0, o2 = 0;
    if (rowok) { o1 = (size_t)b2a[row] * H; o2 = (size_t)b2revb[row] * H; }
    float acc[4][4] = {};
    for (int k0 = 0; k0 < H; k0 += BK) {
        if (rowok) {
            ushort4 u1 = *(const ushort4*)(amsg + o1 + k0 + akq);
            ushort4 u2 = *(const ushort4*)(msg + o2 + k0 + akq);
            As[akq + 0][ar] = b2f(u1.x) - b2f(u2.x);
            As[akq + 1][ar] = b2f(u1.y) - b2f(u2.y);
            As[akq + 2][ar] = b2f(u1.z) - b2f(u2.z);
            As[akq + 3][ar] = b2f(u1.w) - b2f(u2.w);
        } else {
            As[akq + 0][ar] = 0.f; As[akq + 1][ar] = 0.f;
            As[akq + 2][ar] = 0.f; As[akq + 3][ar] = 0.f;
        }
        const int bn = tid & 63, bk = tid >> 6;
        #pragma unroll
        for (int r = 0; r < 4; ++r)
            Bs[bk + 4 * r][bn] = Wh[(size_t)(k0 + bk + 4 * r) * H + n0 + bn];
        __syncthreads();
        #pragma unroll
        for (int kk = 0; kk < BK; ++kk) {
            float4 a = *(const float4*)&As[kk][ty * 4];
            float4 b = *(const float4*)&Bs[kk][tx * 4];
            acc[0][0] = fmaf(a.x, b.x, acc[0][0]); acc[0][1] = fmaf(a.x, b.y, acc[0][1]);
            acc[0][2] = fmaf(a.x, b.z, acc[0][2]); acc[0][3] = fmaf(a.x, b.w, acc[0][3]);
            acc[1][0] = fmaf(a.y, b.x, acc[1][0]); acc[1][1] = fmaf(a.y, b.y, acc[1][1]);
            acc[1][2] = fmaf(a.y, b.z, acc[1][2]); acc[1][3] = fmaf(a.y, b.w, acc[1][3]);
            acc[2][0] = fmaf(a.z, b.x, acc[2][0]); acc[2][1] = fmaf(a.z, b.y, acc[2][1]);
            acc[2][2] = fmaf(a.z, b.z, acc[2][2]); acc[2][3] = fmaf(a.z, b.w, acc[2][3]);
            acc[3][0] = fmaf(a.w, b.x, acc[3][0]); acc[3][1] = fmaf(a.w, b.y, acc[3][1]);
            acc[3][2] = fmaf(a.w, b.z, acc[3][2]); acc[3][3] = fmaf(a.w, b.w, acc[3][3]);
        }
        __syncthreads();
    }
    #pragma unroll
    for (int i = 0; i < 4; ++i) {
        int rr = m0 + ty * 4 + i;
        if (rr >= NBP1) continue;
        size_t off = (size_t)rr * H + n0 + tx * 4;
        ushort4 us = *(const ushort4*)(inp + off);
        ushort4 r;
        r.x = f2b(fmaxf(acc[i][0] + b2f(us.x), 0.f));
        r.y = f2b(fmaxf(acc[i][1] + b2f(us.y), 0.f));
        r.z = f2b(fmaxf(acc[i][2] + b2f(us.z), 0.f));
        r.w = f2b(fmaxf(acc[i][3] + b2f(us.w), 0.f));
        *(ushort4*)(outm + off) = r;
    }
}

// ---------------- GEMM 3: atom_h = relu([f_atoms, nei] @ W_o + b_o) -> f32 ----------------
__global__ __launch_bounds__(256) void gemm_atom_k(
    const float* __restrict__ fa,    // [65536, 133]
    const bf16u* __restrict__ amsg,  // [65536, 256] bf16
    const float* __restrict__ Wo,    // [389, 256]
    const float* __restrict__ bo,    // [256]
    float* __restrict__ C)           // [65536, 256] f32
{
    __shared__ float As[BK][BM + 4];
    __shared__ float Bs[BK][BN];
    const int tid = threadIdx.x;
    const int m0 = blockIdx.y * BM, n0 = blockIdx.x * BN;
    const int tx = tid & 15, ty = tid >> 4;
    const int ar = tid >> 2, akq = (tid & 3) * 4;
    const int row = m0 + ar;
    const int K = ATOM_FDIM + H;  // 389
    float acc[4][4] = {};
    for (int k0 = 0; k0 < K; k0 += BK) {
        #pragma unroll
        for (int j = 0; j < 4; ++j) {
            int kk = k0 + akq + j;
            float v = 0.f;
            if (kk < K) {
                if (kk < ATOM_FDIM) v = fa[(size_t)row * ATOM_FDIM + kk];
                else v = b2f(amsg[(size_t)row * H + (kk - ATOM_FDIM)]);
            }
            As[akq + j][ar] = v;
        }
        const int bn = tid & 63, bk = tid >> 6;
        #pragma unroll
        for (int r = 0; r < 4; ++r) {
            int kk = k0 + bk + 4 * r;
            Bs[bk + 4 * r][bn] = (kk < K) ? Wo[(size_t)kk * H + n0 + bn] : 0.f;
        }
        __syncthreads();
        #pragma unroll
        for (int kk = 0; kk < BK; ++kk) {
            float4 a = *(const float4*)&As[kk][ty * 4];
            float4 b = *(const float4*)&Bs[kk][tx * 4];
            acc[0][0] = fmaf(a.x, b.x, acc[0][0]); acc[0][1] = fmaf(a.x, b.y, acc[0][1]);
            acc[0][2] = fmaf(a.x, b.z, acc[0][2]); acc[0][3] = fmaf(a.x, b.w, acc[0][3]);
            acc[1][0] = fmaf(a.y, b.x, acc[1][0]); acc[1][1] = fmaf(a.y, b.y, acc[1][1]);
            acc[1][2] = fmaf(a.y, b.z, acc[1][2]); acc[1][3] = fmaf(a.y, b.w, acc[1][3]);
            acc[2][0] = fmaf(a.z, b.x, acc[2][0]); acc[2][1] = fmaf(a.z, b.y, acc[2][1]);
            acc[2][2] = fmaf(a.z, b.z, acc[2][2]); acc[2][3] = fmaf(a.z, b.w, acc[2][3]);
            acc[3][0] = fmaf(a.w, b.x, acc[3][0]); acc[3][1] = fmaf(a.w, b.y, acc[3][1]);
            acc[3][2] = fmaf(a.w, b.z, acc[3][2]); acc[3][3] = fmaf(a.w, b.w, acc[3][3]);
        }
        __syncthreads();
    }
    #pragma unroll
    for (int i = 0; i < 4; ++i) {
        int rr = m0 + ty * 4 + i;
        int col = n0 + tx * 4;
        float4 r;
        r.x = fmaxf(acc[i][0] + bo[col + 0], 0.f);
        r.y = fmaxf(acc[i][1] + bo[col + 1], 0.f);
        r.z = fmaxf(acc[i][2] + bo[col + 2], 0.f);
        r.w = fmaxf(acc[i][3] + bo[col + 3], 0.f);
        *(float4*)(C + (size_t)rr * H + col) = r;
    }
}

// ---------------- generic small f32 GEMM ----------------
template<bool BT, bool RELU, bool ADDSRC, bool BIAS>
__global__ __launch_bounds__(256) void gemm_f32_k(
    const float* __restrict__ A, int lda,
    const float* __restrict__ B, int ldb,
    const float* __restrict__ src,
    const float* __restrict__ bias,
    float* __restrict__ C, int ldc,
    int M, int N, int K)
{
    __shared__ float As[BK][BM + 4];
    __shared__ float Bs[BK][BN];
    const int tid = threadIdx.x;
    const int m0 = blockIdx.y * BM, n0 = blockIdx.x * BN;
    const int tx = tid & 15, ty = tid >> 4;
    const int ar = tid >> 2, akq = (tid & 3) * 4;
    const int row = m0 + ar;
    float acc[4][4] = {};
    for (int k0 = 0; k0 < K; k0 += BK) {
        if (row < M && k0 + akq + 3 < K) {
            float4 a4 = *(const float4*)(A + (size_t)row * lda + k0 + akq);
            As[akq + 0][ar] = a4.x; As[akq + 1][ar] = a4.y;
            As[akq + 2][ar] = a4.z; As[akq + 3][ar] = a4.w;
        } else {
            #pragma unroll
            for (int j = 0; j < 4; ++j) {
                int kk = k0 + akq + j;
                As[akq + j][ar] = (row < M && kk < K) ? A[(size_t)row * lda + kk] : 0.f;
            }
        }
        if (!BT) {
            const int bn = tid & 63, bk = tid >> 6;
            #pragma unroll
            for (int r = 0; r < 4; ++r) {
                int kk = k0 + bk + 4 * r;
                Bs[bk + 4 * r][bn] = (kk < K && n0 + bn < N) ? B[(size_t)kk * ldb + n0 + bn] : 0.f;
            }
        } else {
            const int bn = tid >> 2, bk4 = (tid & 3) * 4;
            #pragma unroll
            for (int j = 0; j < 4; ++j) {
                int kk = k0 + bk4 + j;
                Bs[bk4 + j][bn] = (kk < K && n0 + bn < N) ? B[(size_t)(n0 + bn) * ldb + kk] : 0.f;
            }
        }
        __syncthreads();
        #pragma unroll
        for (int kk = 0; kk < BK; ++kk) {
            float4 a = *(const float4*)&As[kk][ty * 4];
            float4 b = *(const float4*)&Bs[kk][tx * 4];
            acc[0][0] = fmaf(a.x, b.x, acc[0][0]); acc[0][1] = fmaf(a.x, b.y, acc[0][1]);
            acc[0][2] = fmaf(a.x, b.z, acc[0][2]); acc[0][3] = fmaf(a.x, b.w, acc[0][3]);
            acc[1][0] = fmaf(a.y, b.x, acc[1][0]); acc[1][1] = fmaf(a.y, b.y, acc[1][1]);
            acc[1][2] = fmaf(a.y, b.z, acc[1][2]); acc[1][3] = fmaf(a.y, b.w, acc[1][3]);
            acc[2][0] = fmaf(a.z, b.x, acc[2][0]); acc[2][1] = fmaf(a.z, b.y, acc[2][1]);
            acc[2][2] = fmaf(a.z, b.z, acc[2][2]); acc[2][3] = fmaf(a.z, b.w, acc[2][3]);
            acc[3][0] = fmaf(a.w, b.x, acc[3][0]); acc[3][1] = fmaf(a.w, b.y, acc[3][1]);
            acc[3][2] = fmaf(a.w, b.z, acc[3][2]); acc[3][3] = fmaf(a.w, b.w, acc[3][3]);
        }
        __syncthreads();
    }
    #pragma unroll
    for (int i = 0; i < 4; ++i) {
        int rr = m0 + ty * 4 + i;
        if (rr >= M) continue;
        #pragma unroll
        for (int j = 0; j < 4; ++j) {
            int col = n0 + tx * 4 + j;
            if (col >= N) continue;
            float v = acc[i][j];
            if (ADDSRC) v += src[(size_t)rr * ldc + col];
            if (BIAS)   v += bias[col];
            if (RELU)   v = fmaxf(v, 0.f);
            C[(size_t)rr * ldc + col] = v;
        }
    }
}

// ---------------- small kernels ----------------
// a_message[na,:] = sum_j message[a2b[na,j], :]   (bf16 in/out, f32 accum)
__global__ __launch_bounds__(256) void gather6_bf16_k(const bf16u* __restrict__ msg,
                                                      const int* __restrict__ a2b,
                                                      bf16u* __restrict__ outb)
{
    int idx = blockIdx.x * 256 + threadIdx.x;
    if (idx >= N_ATOMS * (H / 8)) return;
    int na = idx >> 5, c = idx & 31;
    const int* nb = a2b + (size_t)na * MAX_NB;
    float s[8] = {0.f, 0.f, 0.f, 0.f, 0.f, 0.f, 0.f, 0.f};
    #pragma unroll
    for (int j = 0; j < MAX_NB; ++j) {
        const bf16u* rowp = msg + (size_t)nb[j] * H + c * 8;
        ushort4 u0 = *(const ushort4*)rowp;
        ushort4 u1 = *(const ushort4*)(rowp + 4);
        s[0] += b2f(u0.x); s[1] += b2f(u0.y); s[2] += b2f(u0.z); s[3] += b2f(u0.w);
        s[4] += b2f(u1.x); s[5] += b2f(u1.y); s[6] += b2f(u1.z); s[7] += b2f(u1.w);
    }
    bf16u* op = outb + (size_t)na * H + c * 8;
    ushort4 r0, r1;
    r0.x = f2b(s[0]); r0.y = f2b(s[1]); r0.z = f2b(s[2]); r0.w = f2b(s[3]);
    r1.x = f2b(s[4]); r1.y = f2b(s[5]); r1.z = f2b(s[6]); r1.w = f2b(s[7]);
    *(ushort4*)op = r0;
    *(ushort4*)(op + 4) = r1;
}

__device__ __forceinline__ unsigned int relu2bf(unsigned int w) {
    unsigned int lo = w & 0xFFFFu, hi = w >> 16;
    if (lo & 0x8000u) lo = 0u;
    if (hi & 0x8000u) hi = 0u;
    return lo | (hi << 16);
}

__global__ __launch_bounds__(256) void relu_bf16_k(const bf16u* __restrict__ in,
                                                   bf16u* __restrict__ out, int n8)
{
    int idx = blockIdx.x * 256 + threadIdx.x;
    if (idx >= n8) return;
    uint4 v = ((const uint4*)in)[idx];
    v.x = relu2bf(v.x); v.y = relu2bf(v.y);
    v.z = relu2bf(v.z); v.w = relu2bf(v.w);
    ((uint4*)out)[idx] = v;
}

__global__ __launch_bounds__(256) void zero_bf16_row_k(bf16u* __restrict__ p)
{
    p[threadIdx.x] = 0;
}

__global__ __launch_bounds__(256) void zero_f32_k(float* __restrict__ p, int n)
{
    int idx = blockIdx.x * 256 + threadIdx.x;
    if (idx < n) p[idx] = 0.f;
}

__device__ __forceinline__ float sigm(float x) { return 1.f / (1.f + expf(-x)); }

__global__ __launch_bounds__(256) void lstm_pw_k(const float* __restrict__ gates,
                                                 float* __restrict__ h,
                                                 float* __restrict__ c, int M)
{
    int idx = blockIdx.x * 256 + threadIdx.x;
    if (idx >= M * H) return;
    int m = idx >> 8, d = idx & 255;
    const float* g = gates + (size_t)m * (4 * H);
    float ig = sigm(g[d]);
    float fg = sigm(g[H + d]);
    float gg = tanhf(g[2 * H + d]);
    float og = sigm(g[3 * H + d]);
    float cn = fg * c[idx] + ig * gg;
    c[idx] = cn;
    h[idx] = og * tanhf(cn);
}

// per-molecule attention + readout; q_star[m] = [h[m], readout]
__global__ __launch_bounds__(256) void s2s_attn_k(const float* __restrict__ feat,
                                                  const float* __restrict__ h,
                                                  float* __restrict__ q_star, int Nn)
{
    int m = blockIdx.x;
    int t = threadIdx.x;
    int lane = t & 63, wave = t >> 6;
    __shared__ float sc[32];
    const float* f = feat + (size_t)m * Nn * H;
    const float* hm = h + (size_t)m * H;
    for (int n = wave; n < Nn; n += 4) {
        const float* fr = f + (size_t)n * H;
        float p = 0.f;
        #pragma unroll
        for (int u = 0; u < 4; ++u) p += fr[lane * 4 + u] * hm[lane * 4 + u];
        #pragma unroll
        for (int o = 32; o >= 1; o >>= 1) p += __shfl_xor(p, o);
        if (lane == 0) sc[n] = p;
    }
    __syncthreads();
    float mx = -1e30f;
    for (int n = 0; n < Nn; ++n) mx = fmaxf(mx, sc[n]);
    float ssum = 0.f, r = 0.f;
    for (int n = 0; n < Nn; ++n) {
        float a = expf(sc[n] - mx);
        ssum += a;
        r += a * f[(size_t)n * H + t];
    }
    r /= ssum;
    q_star[(size_t)m * (2 * H) + t] = hm[t];
    q_star[(size_t)m * (2 * H) + H + t] = r;
}

// X[b,s1,s2,:] = (s1==s2) ? SO[b,s1,:] : P[b,s1,:] + Q[b,s2,:] + b0
__global__ __launch_bounds__(256) void build_x_k(const float* __restrict__ P,
                                                 const float* __restrict__ Q,
                                                 const float* __restrict__ SO,
                                                 const float* __restrict__ b0,
                                                 float* __restrict__ X)
{
    int idx = blockIdx.x * 256 + threadIdx.x;
    if (idx >= B_RXN * S_STEPS * S_STEPS * H) return;
    int d  = idx & 255;
    int s2 = (idx >> 8) & 3;
    int s1 = (idx >> 10) & 3;
    int b  = idx >> 12;
    float v;
    if (s1 == s2) v = SO[((size_t)b * S_STEPS + s1) * H + d];
    else v = P[((size_t)b * S_STEPS + s1) * H + d] + Q[((size_t)b * S_STEPS + s2) * H + d] + b0[d];
    X[idx] = v;
}

// ---------------- launch ----------------
extern "C" void kernel_launch(void* const* d_in, const int* in_sizes, int n_in,
                              void* d_out, int out_size, void* d_ws, size_t ws_size,
                              hipStream_t stream)
{
    const float* f_atoms   = (const float*)d_in[0];
    const float* f_bonds   = (const float*)d_in[1];
    const int*   a2b       = (const int*)d_in[2];
    const int*   b2a       = (const int*)d_in[3];
    const int*   b2revb    = (const int*)d_in[4];
    const float* W_i       = (const float*)d_in[5];
    const float* W_h       = (const float*)d_in[6];
    const float* W_o       = (const float*)d_in[7];
    const float* b_o       = (const float*)d_in[8];
    const float* W_nn0     = (const float*)d_in[9];
    const float* b_nn0     = (const float*)d_in[10];
    const float* W_nn0s    = (const float*)d_in[11];
    const float* b_nn0s    = (const float*)d_in[12];
    const float* W_nn1     = (const float*)d_in[13];
    const float* b_nn1     = (const float*)d_in[14];
    const float* lstm_n_Wih = (const float*)d_in[15];
    const float* lstm_n_Whh = (const float*)d_in[16];
    const float* lstm_n_b   = (const float*)d_in[17];
    const float* node_cond_W = (const float*)d_in[18];
    const float* node_cond_b = (const float*)d_in[19];
    const float* lstm_g_Wih = (const float*)d_in[20];
    const float* lstm_g_Whh = (const float*)d_in[21];
    const float* lstm_g_b   = (const float*)d_in[22];
    const float* graph_cond_W = (const float*)d_in[23];
    const float* graph_cond_b = (const float*)d_in[24];
    float* out = (float*)d_out;

    // ---- workspace layout (bytes). total = 234,882,560 B (~224 MiB) ----
    const size_t SZB = (size_t)NBP1 * H * sizeof(bf16u);    // 67,109,376
    char* base = (char*)d_ws;
    bf16u* INP  = (bf16u*)(base);
    bf16u* MSGA = (bf16u*)(base + SZB);
    bf16u* MSGB = (bf16u*)(base + 2 * SZB);
    bf16u* AMSG = (bf16u*)(base + 3 * SZB);                 // [N_ATOMS,H] bf16
    // aliases (regions dead at time of use):
    float* ATOMH = (float*)(base);                          // [N_ATOMS,H] f32, alias INP
    float* SMALL = (float*)(base + SZB);                    // f32 scratch, alias MSGA
    float* GATES  = SMALL;                                  // [2048,1024]
    float* HN     = SMALL + 2097152;                        // [2048,256]
    float* CN     = SMALL + 2621440;                        // [2048,256]
    float* QSTARN = SMALL + 3145728;                        // [2048,512]
    float* MOL    = SMALL + 4194304;                        // [2048,256]
    float* PP     = SMALL + 4718592;                        // [2048,256]
    float* QQ     = SMALL + 5242880;                        // [2048,256]
    float* SO     = SMALL + 5767168;                        // [2048,256]
    float* XBUF   = SMALL + 6291456;                        // [8192,256]
    float* STEPS  = SMALL + 8388608;                        // [2048,256]
    float* HG     = SMALL + 8912896;                        // [512,256]
    float* CG     = SMALL + 9043968;                        // [512,256]
    float* QSTARG = SMALL + 9175040;                        // [512,512]
    float* GATESG = SMALL + 9437184;                        // [512,1024]

    dim3 blk(256);
    auto g2d = [](int M, int N) { return dim3((unsigned)((N + BN - 1) / BN), (unsigned)((M + BM - 1) / BM)); };

    // 1. inp = f_bonds @ W_i  (row 0 stays 0 since f_bonds[0]=0, no bias)
    gemm_wi_k<<<g2d(NBP1, H), blk, 0, stream>>>(f_bonds, W_i, INP);
    // message = relu(inp)
    relu_bf16_k<<<(NBP1 * H / 8 + 255) / 256, blk, 0, stream>>>(INP, MSGA, NBP1 * H / 8);

    // 2. depth loop
    bf16u* cur = MSGA; bf16u* nxt = MSGB;
    for (int d = 0; d < DEPTH - 1; ++d) {
        gather6_bf16_k<<<(N_ATOMS * (H / 8) + 255) / 256, blk, 0, stream>>>(cur, a2b, AMSG);
        gemm_msg_k<<<g2d(NBP1, H), blk, 0, stream>>>(AMSG, cur, INP, W_h, b2a, b2revb, nxt);
        zero_bf16_row_k<<<1, 256, 0, stream>>>(nxt);
        bf16u* t = cur; cur = nxt; nxt = t;
    }

    // 3. nei = gather-sum(final message)  (final message is in MSGA)
    gather6_bf16_k<<<(N_ATOMS * (H / 8) + 255) / 256, blk, 0, stream>>>(cur, a2b, AMSG);

    // 4. atom_h (f32, aliases INP region; INP dead now)
    gemm_atom_k<<<g2d(N_ATOMS, H), blk, 0, stream>>>(f_atoms, AMSG, W_o, b_o, ATOMH);

    // 5. node Set2Set over [2048, 32, 256]
    zero_f32_k<<<(2097152 + 255) / 256, blk, 0, stream>>>(HN, 2097152);  // HN,CN,QSTARN contiguous
    for (int it = 0; it < N_ITERS; ++it) {
        gemm_f32_k<true, false, false, false><<<g2d(N_MOLS, 4 * H), blk, 0, stream>>>(
            QSTARN, 2 * H, lstm_n_Wih, 2 * H, nullptr, nullptr, GATES, 4 * H, N_MOLS, 4 * H, 2 * H);
        gemm_f32_k<true, false, true, true><<<g2d(N_MOLS, 4 * H), blk, 0, stream>>>(
            HN, H, lstm_n_Whh, H, GATES, lstm_n_b, GATES, 4 * H, N_MOLS, 4 * H, H);
        lstm_pw_k<<<(N_MOLS * H) / 256, blk, 0, stream>>>(GATES, HN, CN, N_MOLS);
        s2s_attn_k<<<N_MOLS, blk, 0, stream>>>(ATOMH, HN, QSTARN, ATOMS_PER_MOL);
    }
    gemm_f32_k<false, false, false, true><<<g2d(N_MOLS, H), blk, 0, stream>>>(
        QSTARN, 2 * H, node_cond_W, H, nullptr, node_cond_b, MOL, H, N_MOLS, H, 2 * H);

    // 6. NN attention over steps
    gemm_f32_k<false, false, false, false><<<g2d(N_MOLS, H), blk, 0, stream>>>(
        MOL, H, W_nn0, H, nullptr, nullptr, PP, H, N_MOLS, H, H);
    gemm_f32_k<false, false, false, false><<<g2d(N_MOLS, H), blk, 0, stream>>>(
        MOL, H, W_nn0 + (size_t)H * H, H, nullptr, nullptr, QQ, H, N_MOLS, H, H);
    gemm_f32_k<false, false, false, true><<<g2d(N_MOLS, H), blk, 0, stream>>>(
        MOL, H, W_nn0s, H, nullptr, b_nn0s, SO, H, N_MOLS, H, H);
    build_x_k<<<(B_RXN * 16 * H) / 256, blk, 0, stream>>>(PP, QQ, SO, b_nn0, XBUF);
    gemm_f32_k<false, false, false, true><<<g2d(N_MOLS, H), blk, 0, stream>>>(
        XBUF, S_STEPS * H, W_nn1, H, nullptr, b_nn1, STEPS, H, N_MOLS, H, S_STEPS * H);

    // 7. graph Set2Set over [512, 4, 256]
    zero_f32_k<<<(524288 + 255) / 256, blk, 0, stream>>>(HG, 524288);    // HG,CG,QSTARG contiguous
    for (int it = 0; it < N_ITERS; ++it) {
        gemm_f32_k<true, false, false, false><<<g2d(B_RXN, 4 * H), blk, 0, stream>>>(
            QSTARG, 2 * H, lstm_g_Wih, 2 * H, nullptr, nullptr, GATESG, 4 * H, B_RXN, 4 * H, 2 * H);
        gemm_f32_k<true, false, true, true><<<g2d(B_RXN, 4 * H), blk, 0, stream>>>(
            HG, H, lstm_g_Whh, H, GATESG, lstm_g_b, GATESG, 4 * H, B_RXN, 4 * H, H);
        lstm_pw_k<<<(B_RXN * H) / 256, blk, 0, stream>>>(GATESG, HG, CG, B_RXN);
        s2s_attn_k<<<B_RXN, blk, 0, stream>>>(STEPS, HG, QSTARG, S_STEPS);
    }

    // 8. out
    gemm_f32_k<false, false, false, true><<<g2d(B_RXN, H), blk, 0, stream>>>(
        QSTARG, 2 * H, graph_cond_W, H, nullptr, graph_cond_b, out, H, B_RXN, H, 2 * H);
}

// Round 3
// 1513.881 us; speedup vs baseline: 1.4212x; 1.4212x over previous
//
#include <hip/hip_runtime.h>
#include <math.h>

// ---------------- problem constants ----------------
#define H 256
#define S_STEPS 4
#define B_RXN 512
#define N_MOLS 2048          // B*S
#define ATOMS_PER_MOL 32
#define N_ATOMS 65536        // N_MOLS*32
#define N_BONDS 131072
#define NBP1 131073          // N_BONDS+1
#define MAX_NB 6
#define ATOM_FDIM 133
#define BOND_FDIM 147
#define DEPTH 3
#define N_ITERS 3

typedef unsigned short bf16u;
typedef __attribute__((ext_vector_type(8))) short short8v;  // 8 bf16 = 4 VGPR
typedef __attribute__((ext_vector_type(4))) float f32x4;

__device__ __forceinline__ float b2f(bf16u u) {
    union { unsigned int i; float f; } c; c.i = ((unsigned int)u) << 16; return c.f;
}
__device__ __forceinline__ bf16u f2b(float f) {
    union { float f; unsigned int i; } c; c.f = f;
    unsigned int i = c.i;
    return (bf16u)((i + 0x7FFFu + ((i >> 16) & 1u)) >> 16);   // RNE
}

// ================= MFMA bf16 GEMM: C[M,256] = epi(A[M,K] @ B[K,256]) =================
// MODE 0 (WI):   A = f_bonds f32 [M,147] (KP=160);      epi: outb=bf16(acc), outb2=bf16(relu(acc))
// MODE 1 (MSG):  A = amsg[b2a[r]] - msg[b2revb[r]] bf16 (KP=256); epi: relu(acc+inp), row0=0 -> outb
// MODE 2 (ATOM): A = [f_atoms f32 133 | pad | amsg bf16 256] (KP=416); epi: relu(acc+bias) -> outf
// Block: 256 thr = 4 waves; BM=64, BN=256 (full N). Wave w covers cols w*64..+63.
template<int MODE>
__global__ __launch_bounds__(256) void mfma_gemm_k(
    const float* __restrict__ Af32,
    const bf16u* __restrict__ amsg,
    const bf16u* __restrict__ msgp,
    const bf16u* __restrict__ inp,
    const bf16u* __restrict__ WT,     // [256][KP] bf16 (pre-transposed, padded)
    const float* __restrict__ bias,
    const int* __restrict__ b2a,
    const int* __restrict__ b2revb,
    float* __restrict__ outf,
    bf16u* __restrict__ outb,
    bf16u* __restrict__ outb2,
    int M)
{
    constexpr int KP = (MODE == 0) ? 160 : ((MODE == 1) ? 256 : 416);
    __shared__ bf16u As[64][40];    // row-major [m][k], +8 pad (80B stride)
    __shared__ bf16u Bs[256][40];   // [n][k] (B transposed), +8 pad

    const int tid = threadIdx.x;
    const int lane = tid & 63, w = tid >> 6;
    const int m0 = blockIdx.x * 64;
    const int ar = tid >> 2, ac8 = (tid & 3) * 8;   // A stage: row, k-chunk
    const int arow = m0 + ar;
    const bool rok = arow < M;
    size_t o1 = 0, o2 = 0;
    if (MODE == 1 && rok) {
        o1 = (size_t)b2a[arow] * H;
        o2 = (size_t)b2revb[arow] * H;
    }
    const int lr = lane & 15, lk = (lane >> 4) * 8;

    f32x4 acc[4][4];
    const f32x4 zf = {0.f, 0.f, 0.f, 0.f};
    #pragma unroll
    for (int i = 0; i < 4; ++i)
        #pragma unroll
        for (int j = 0; j < 4; ++j) acc[i][j] = zf;

    for (int k0 = 0; k0 < KP; k0 += 32) {
        // ---- stage A (64 x 32 bf16) ----
        ushort4 s0, s1;
        if (MODE == 1) {
            if (rok) {
                ushort4 ua0 = *(const ushort4*)(amsg + o1 + k0 + ac8);
                ushort4 ua1 = *(const ushort4*)(amsg + o1 + k0 + ac8 + 4);
                ushort4 ub0 = *(const ushort4*)(msgp + o2 + k0 + ac8);
                ushort4 ub1 = *(const ushort4*)(msgp + o2 + k0 + ac8 + 4);
                s0.x = f2b(b2f(ua0.x) - b2f(ub0.x)); s0.y = f2b(b2f(ua0.y) - b2f(ub0.y));
                s0.z = f2b(b2f(ua0.z) - b2f(ub0.z)); s0.w = f2b(b2f(ua0.w) - b2f(ub0.w));
                s1.x = f2b(b2f(ua1.x) - b2f(ub1.x)); s1.y = f2b(b2f(ua1.y) - b2f(ub1.y));
                s1.z = f2b(b2f(ua1.z) - b2f(ub1.z)); s1.w = f2b(b2f(ua1.w) - b2f(ub1.w));
            } else {
                s0 = make_ushort4(0, 0, 0, 0); s1 = make_ushort4(0, 0, 0, 0);
            }
        } else {
            float v[8];
            #pragma unroll
            for (int j = 0; j < 8; ++j) {
                int kk = k0 + ac8 + j;
                float x = 0.f;
                if (rok) {
                    if (MODE == 0) {
                        if (kk < BOND_FDIM) x = Af32[(size_t)arow * BOND_FDIM + kk];
                    } else {
                        if (kk < ATOM_FDIM) x = Af32[(size_t)arow * ATOM_FDIM + kk];
                        else if (kk >= 160) x = b2f(amsg[(size_t)arow * H + (kk - 160)]);
                    }
                }
                v[j] = x;
            }
            s0.x = f2b(v[0]); s0.y = f2b(v[1]); s0.z = f2b(v[2]); s0.w = f2b(v[3]);
            s1.x = f2b(v[4]); s1.y = f2b(v[5]); s1.z = f2b(v[6]); s1.w = f2b(v[7]);
        }
        *(ushort4*)&As[ar][ac8] = s0;
        *(ushort4*)&As[ar][ac8 + 4] = s1;

        // ---- stage B (256 n x 32 k): thread t = row n of WT ----
        {
            const bf16u* bp = WT + (size_t)tid * KP + k0;
            uint4 q0 = *(const uint4*)(bp);
            uint4 q1 = *(const uint4*)(bp + 8);
            uint4 q2 = *(const uint4*)(bp + 16);
            uint4 q3 = *(const uint4*)(bp + 24);
            *(uint4*)&Bs[tid][0]  = q0;
            *(uint4*)&Bs[tid][8]  = q1;
            *(uint4*)&Bs[tid][16] = q2;
            *(uint4*)&Bs[tid][24] = q3;
        }
        __syncthreads();

        // ---- compute: 16 MFMA per wave per k-step ----
        short8v a[4], b[4];
        #pragma unroll
        for (int mf = 0; mf < 4; ++mf)
            a[mf] = *(const short8v*)&As[mf * 16 + lr][lk];
        #pragma unroll
        for (int nf = 0; nf < 4; ++nf)
            b[nf] = *(const short8v*)&Bs[w * 64 + nf * 16 + lr][lk];
        #pragma unroll
        for (int mf = 0; mf < 4; ++mf)
            #pragma unroll
            for (int nf = 0; nf < 4; ++nf)
                acc[mf][nf] = __builtin_amdgcn_mfma_f32_16x16x32_bf16(
                    a[mf], b[nf], acc[mf][nf], 0, 0, 0);
        __syncthreads();
    }

    // ---- epilogue ----
    const int rbase = (lane >> 4) * 4;
    #pragma unroll
    for (int mf = 0; mf < 4; ++mf) {
        #pragma unroll
        for (int nf = 0; nf < 4; ++nf) {
            const int col = w * 64 + nf * 16 + lr;
            #pragma unroll
            for (int r = 0; r < 4; ++r) {
                const int row = m0 + mf * 16 + rbase + r;
                if (row >= M) continue;
                float v = acc[mf][nf][r];
                const size_t off = (size_t)row * H + col;
                if (MODE == 0) {
                    outb[off] = f2b(v);
                    outb2[off] = f2b(fmaxf(v, 0.f));
                } else if (MODE == 1) {
                    v += b2f(inp[off]);
                    v = fmaxf(v, 0.f);
                    outb[off] = (row == 0) ? (bf16u)0 : f2b(v);
                } else {
                    v += bias[col];
                    v = fmaxf(v, 0.f);
                    outf[off] = v;
                }
            }
        }
    }
}

// ---------------- weight prep: WT[n][k] = bf16(W[k][n]), zero-padded ----------------
__global__ __launch_bounds__(256) void prep_wt_k(const float* __restrict__ W,
                                                 bf16u* __restrict__ WT, int K, int KP)
{
    int idx = blockIdx.x * 256 + threadIdx.x;
    if (idx >= 256 * KP) return;
    int n = idx / KP, k = idx - n * KP;
    WT[idx] = (k < K) ? f2b(W[(size_t)k * H + n]) : (bf16u)0;
}

// W_o variant: logical k<133 -> Wo[k]; k in [133,160) -> 0; k>=160 -> Wo[133+k-160]
__global__ __launch_bounds__(256) void prep_wto_k(const float* __restrict__ Wo,
                                                  bf16u* __restrict__ WT)
{
    int idx = blockIdx.x * 256 + threadIdx.x;
    if (idx >= 256 * 416) return;
    int n = idx / 416, k = idx - n * 416;
    float v = 0.f;
    if (k < ATOM_FDIM) v = Wo[(size_t)k * H + n];
    else if (k >= 160) v = Wo[(size_t)(ATOM_FDIM + k - 160) * H + n];
    WT[idx] = f2b(v);
}

// ---------------- generic small f32 GEMM (unchanged, passing) ----------------
constexpr int BM = 64, BN = 64, BK = 16;
template<bool BT, bool RELU, bool ADDSRC, bool BIAS>
__global__ __launch_bounds__(256) void gemm_f32_k(
    const float* __restrict__ A, int lda,
    const float* __restrict__ B, int ldb,
    const float* __restrict__ src,
    const float* __restrict__ bias,
    float* __restrict__ C, int ldc,
    int M, int N, int K)
{
    __shared__ float As[BK][BM + 4];
    __shared__ float Bs[BK][BN];
    const int tid = threadIdx.x;
    const int m0 = blockIdx.y * BM, n0 = blockIdx.x * BN;
    const int tx = tid & 15, ty = tid >> 4;
    const int ar = tid >> 2, akq = (tid & 3) * 4;
    const int row = m0 + ar;
    float acc[4][4] = {};
    for (int k0 = 0; k0 < K; k0 += BK) {
        if (row < M && k0 + akq + 3 < K) {
            float4 a4 = *(const float4*)(A + (size_t)row * lda + k0 + akq);
            As[akq + 0][ar] = a4.x; As[akq + 1][ar] = a4.y;
            As[akq + 2][ar] = a4.z; As[akq + 3][ar] = a4.w;
        } else {
            #pragma unroll
            for (int j = 0; j < 4; ++j) {
                int kk = k0 + akq + j;
                As[akq + j][ar] = (row < M && kk < K) ? A[(size_t)row * lda + kk] : 0.f;
            }
        }
        if (!BT) {
            const int bn = tid & 63, bk = tid >> 6;
            #pragma unroll
            for (int r = 0; r < 4; ++r) {
                int kk = k0 + bk + 4 * r;
                Bs[bk + 4 * r][bn] = (kk < K && n0 + bn < N) ? B[(size_t)kk * ldb + n0 + bn] : 0.f;
            }
        } else {
            const int bn = tid >> 2, bk4 = (tid & 3) * 4;
            #pragma unroll
            for (int j = 0; j < 4; ++j) {
                int kk = k0 + bk4 + j;
                Bs[bk4 + j][bn] = (kk < K && n0 + bn < N) ? B[(size_t)(n0 + bn) * ldb + kk] : 0.f;
            }
        }
        __syncthreads();
        #pragma unroll
        for (int kk = 0; kk < BK; ++kk) {
            float4 a = *(const float4*)&As[kk][ty * 4];
            float4 b = *(const float4*)&Bs[kk][tx * 4];
            acc[0][0] = fmaf(a.x, b.x, acc[0][0]); acc[0][1] = fmaf(a.x, b.y, acc[0][1]);
            acc[0][2] = fmaf(a.x, b.z, acc[0][2]); acc[0][3] = fmaf(a.x, b.w, acc[0][3]);
            acc[1][0] = fmaf(a.y, b.x, acc[1][0]); acc[1][1] = fmaf(a.y, b.y, acc[1][1]);
            acc[1][2] = fmaf(a.y, b.z, acc[1][2]); acc[1][3] = fmaf(a.y, b.w, acc[1][3]);
            acc[2][0] = fmaf(a.z, b.x, acc[2][0]); acc[2][1] = fmaf(a.z, b.y, acc[2][1]);
            acc[2][2] = fmaf(a.z, b.z, acc[2][2]); acc[2][3] = fmaf(a.z, b.w, acc[2][3]);
            acc[3][0] = fmaf(a.w, b.x, acc[3][0]); acc[3][1] = fmaf(a.w, b.y, acc[3][1]);
            acc[3][2] = fmaf(a.w, b.z, acc[3][2]); acc[3][3] = fmaf(a.w, b.w, acc[3][3]);
        }
        __syncthreads();
    }
    #pragma unroll
    for (int i = 0; i < 4; ++i) {
        int rr = m0 + ty * 4 + i;
        if (rr >= M) continue;
        #pragma unroll
        for (int j = 0; j < 4; ++j) {
            int col = n0 + tx * 4 + j;
            if (col >= N) continue;
            float v = acc[i][j];
            if (ADDSRC) v += src[(size_t)rr * ldc + col];
            if (BIAS)   v += bias[col];
            if (RELU)   v = fmaxf(v, 0.f);
            C[(size_t)rr * ldc + col] = v;
        }
    }
}

// ---------------- small kernels ----------------
__global__ __launch_bounds__(256) void gather6_bf16_k(const bf16u* __restrict__ msg,
                                                      const int* __restrict__ a2b,
                                                      bf16u* __restrict__ outb)
{
    int idx = blockIdx.x * 256 + threadIdx.x;
    if (idx >= N_ATOMS * (H / 8)) return;
    int na = idx >> 5, c = idx & 31;
    const int* nb = a2b + (size_t)na * MAX_NB;
    float s[8] = {0.f, 0.f, 0.f, 0.f, 0.f, 0.f, 0.f, 0.f};
    #pragma unroll
    for (int j = 0; j < MAX_NB; ++j) {
        const bf16u* rowp = msg + (size_t)nb[j] * H + c * 8;
        ushort4 u0 = *(const ushort4*)rowp;
        ushort4 u1 = *(const ushort4*)(rowp + 4);
        s[0] += b2f(u0.x); s[1] += b2f(u0.y); s[2] += b2f(u0.z); s[3] += b2f(u0.w);
        s[4] += b2f(u1.x); s[5] += b2f(u1.y); s[6] += b2f(u1.z); s[7] += b2f(u1.w);
    }
    bf16u* op = outb + (size_t)na * H + c * 8;
    ushort4 r0, r1;
    r0.x = f2b(s[0]); r0.y = f2b(s[1]); r0.z = f2b(s[2]); r0.w = f2b(s[3]);
    r1.x = f2b(s[4]); r1.y = f2b(s[5]); r1.z = f2b(s[6]); r1.w = f2b(s[7]);
    *(ushort4*)op = r0;
    *(ushort4*)(op + 4) = r1;
}

__global__ __launch_bounds__(256) void zero_f32_k(float* __restrict__ p, int n)
{
    int idx = blockIdx.x * 256 + threadIdx.x;
    if (idx < n) p[idx] = 0.f;
}

__device__ __forceinline__ float sigm(float x) { return 1.f / (1.f + expf(-x)); }

__global__ __launch_bounds__(256) void lstm_pw_k(const float* __restrict__ gates,
                                                 float* __restrict__ h,
                                                 float* __restrict__ c, int M)
{
    int idx = blockIdx.x * 256 + threadIdx.x;
    if (idx >= M * H) return;
    int m = idx >> 8, d = idx & 255;
    const float* g = gates + (size_t)m * (4 * H);
    float ig = sigm(g[d]);
    float fg = sigm(g[H + d]);
    float gg = tanhf(g[2 * H + d]);
    float og = sigm(g[3 * H + d]);
    float cn = fg * c[idx] + ig * gg;
    c[idx] = cn;
    h[idx] = og * tanhf(cn);
}

__global__ __launch_bounds__(256) void s2s_attn_k(const float* __restrict__ feat,
                                                  const float* __restrict__ h,
                                                  float* __restrict__ q_star, int Nn)
{
    int m = blockIdx.x;
    int t = threadIdx.x;
    int lane = t & 63, wave = t >> 6;
    __shared__ float sc[32];
    const float* f = feat + (size_t)m * Nn * H;
    const float* hm = h + (size_t)m * H;
    for (int n = wave; n < Nn; n += 4) {
        const float* fr = f + (size_t)n * H;
        float p = 0.f;
        #pragma unroll
        for (int u = 0; u < 4; ++u) p += fr[lane * 4 + u] * hm[lane * 4 + u];
        #pragma unroll
        for (int o = 32; o >= 1; o >>= 1) p += __shfl_xor(p, o);
        if (lane == 0) sc[n] = p;
    }
    __syncthreads();
    float mx = -1e30f;
    for (int n = 0; n < Nn; ++n) mx = fmaxf(mx, sc[n]);
    float ssum = 0.f, r = 0.f;
    for (int n = 0; n < Nn; ++n) {
        float a = expf(sc[n] - mx);
        ssum += a;
        r += a * f[(size_t)n * H + t];
    }
    r /= ssum;
    q_star[(size_t)m * (2 * H) + t] = hm[t];
    q_star[(size_t)m * (2 * H) + H + t] = r;
}

__global__ __launch_bounds__(256) void build_x_k(const float* __restrict__ P,
                                                 const float* __restrict__ Q,
                                                 const float* __restrict__ SO,
                                                 const float* __restrict__ b0,
                                                 float* __restrict__ X)
{
    int idx = blockIdx.x * 256 + threadIdx.x;
    if (idx >= B_RXN * S_STEPS * S_STEPS * H) return;
    int d  = idx & 255;
    int s2 = (idx >> 8) & 3;
    int s1 = (idx >> 10) & 3;
    int b  = idx >> 12;
    float v;
    if (s1 == s2) v = SO[((size_t)b * S_STEPS + s1) * H + d];
    else v = P[((size_t)b * S_STEPS + s1) * H + d] + Q[((size_t)b * S_STEPS + s2) * H + d] + b0[d];
    X[idx] = v;
}

// ---------------- launch ----------------
extern "C" void kernel_launch(void* const* d_in, const int* in_sizes, int n_in,
                              void* d_out, int out_size, void* d_ws, size_t ws_size,
                              hipStream_t stream)
{
    const float* f_atoms   = (const float*)d_in[0];
    const float* f_bonds   = (const float*)d_in[1];
    const int*   a2b       = (const int*)d_in[2];
    const int*   b2a       = (const int*)d_in[3];
    const int*   b2revb    = (const int*)d_in[4];
    const float* W_i       = (const float*)d_in[5];
    const float* W_h       = (const float*)d_in[6];
    const float* W_o       = (const float*)d_in[7];
    const float* b_o       = (const float*)d_in[8];
    const float* W_nn0     = (const float*)d_in[9];
    const float* b_nn0     = (const float*)d_in[10];
    const float* W_nn0s    = (const float*)d_in[11];
    const float* b_nn0s    = (const float*)d_in[12];
    const float* W_nn1     = (const float*)d_in[13];
    const float* b_nn1     = (const float*)d_in[14];
    const float* lstm_n_Wih = (const float*)d_in[15];
    const float* lstm_n_Whh = (const float*)d_in[16];
    const float* lstm_n_b   = (const float*)d_in[17];
    const float* node_cond_W = (const float*)d_in[18];
    const float* node_cond_b = (const float*)d_in[19];
    const float* lstm_g_Wih = (const float*)d_in[20];
    const float* lstm_g_Whh = (const float*)d_in[21];
    const float* lstm_g_b   = (const float*)d_in[22];
    const float* graph_cond_W = (const float*)d_in[23];
    const float* graph_cond_b = (const float*)d_in[24];
    float* out = (float*)d_out;

    // ---- workspace layout ----
    const size_t SZB = (size_t)NBP1 * H * sizeof(bf16u);    // 67,109,376
    char* base = (char*)d_ws;
    bf16u* INP  = (bf16u*)(base);
    bf16u* MSGA = (bf16u*)(base + SZB);
    bf16u* MSGB = (bf16u*)(base + 2 * SZB);
    bf16u* AMSG = (bf16u*)(base + 3 * SZB);                 // [N_ATOMS,H] bf16 (33,554,432 B)
    bf16u* WT_I = (bf16u*)(base + 3 * SZB + 33554432);      // [256][160] =  81,920 B
    bf16u* WT_H = (bf16u*)(base + 3 * SZB + 33636352);      // [256][256] = 131,072 B
    bf16u* WT_O = (bf16u*)(base + 3 * SZB + 33767424);      // [256][416] = 212,992 B
    // aliases (dead regions at time of use):
    float* ATOMH = (float*)(base);                          // [N_ATOMS,H] f32, alias INP
    float* SMALL = (float*)(base + SZB);                    // f32 scratch, alias MSGA
    float* GATES  = SMALL;
    float* HN     = SMALL + 2097152;
    float* CN     = SMALL + 2621440;
    float* QSTARN = SMALL + 3145728;
    float* MOL    = SMALL + 4194304;
    float* PP     = SMALL + 4718592;
    float* QQ     = SMALL + 5242880;
    float* SO     = SMALL + 5767168;
    float* XBUF   = SMALL + 6291456;
    float* STEPS  = SMALL + 8388608;
    float* HG     = SMALL + 8912896;
    float* CG     = SMALL + 9043968;
    float* QSTARG = SMALL + 9175040;
    float* GATESG = SMALL + 9437184;

    dim3 blk(256);
    auto g2d = [](int M, int N) { return dim3((unsigned)((N + BN - 1) / BN), (unsigned)((M + BM - 1) / BM)); };
    const int MB_BOND = (NBP1 + 63) / 64;     // 2049
    const int MB_ATOM = N_ATOMS / 64;         // 1024

    // 0. weight prep (bf16, transposed, padded)
    prep_wt_k<<<(256 * 160 + 255) / 256, blk, 0, stream>>>(W_i, WT_I, BOND_FDIM, 160);
    prep_wt_k<<<(256 * 256 + 255) / 256, blk, 0, stream>>>(W_h, WT_H, H, 256);
    prep_wto_k<<<(256 * 416 + 255) / 256, blk, 0, stream>>>(W_o, WT_O);

    // 1. inp = f_bonds @ W_i -> INP (bf16) ; MSGA = relu(inp) (fused)
    mfma_gemm_k<0><<<MB_BOND, blk, 0, stream>>>(
        f_bonds, nullptr, nullptr, nullptr, WT_I, nullptr, nullptr, nullptr,
        nullptr, INP, MSGA, NBP1);

    // 2. depth loop
    bf16u* cur = MSGA; bf16u* nxt = MSGB;
    for (int d = 0; d < DEPTH - 1; ++d) {
        gather6_bf16_k<<<(N_ATOMS * (H / 8) + 255) / 256, blk, 0, stream>>>(cur, a2b, AMSG);
        mfma_gemm_k<1><<<MB_BOND, blk, 0, stream>>>(
            nullptr, AMSG, cur, INP, WT_H, nullptr, b2a, b2revb,
            nullptr, nxt, nullptr, NBP1);
        bf16u* t = cur; cur = nxt; nxt = t;
    }

    // 3. nei = gather-sum(final message)
    gather6_bf16_k<<<(N_ATOMS * (H / 8) + 255) / 256, blk, 0, stream>>>(cur, a2b, AMSG);

    // 4. atom_h = relu([f_atoms, nei] @ W_o + b_o) -> ATOMH f32 (aliases dead INP)
    mfma_gemm_k<2><<<MB_ATOM, blk, 0, stream>>>(
        f_atoms, AMSG, nullptr, nullptr, WT_O, b_o, nullptr, nullptr,
        ATOMH, nullptr, nullptr, N_ATOMS);

    // 5. node Set2Set over [2048, 32, 256]
    zero_f32_k<<<(2097152 + 255) / 256, blk, 0, stream>>>(HN, 2097152);  // HN,CN,QSTARN
    for (int it = 0; it < N_ITERS; ++it) {
        gemm_f32_k<true, false, false, false><<<g2d(N_MOLS, 4 * H), blk, 0, stream>>>(
            QSTARN, 2 * H, lstm_n_Wih, 2 * H, nullptr, nullptr, GATES, 4 * H, N_MOLS, 4 * H, 2 * H);
        gemm_f32_k<true, false, true, true><<<g2d(N_MOLS, 4 * H), blk, 0, stream>>>(
            HN, H, lstm_n_Whh, H, GATES, lstm_n_b, GATES, 4 * H, N_MOLS, 4 * H, H);
        lstm_pw_k<<<(N_MOLS * H) / 256, blk, 0, stream>>>(GATES, HN, CN, N_MOLS);
        s2s_attn_k<<<N_MOLS, blk, 0, stream>>>(ATOMH, HN, QSTARN, ATOMS_PER_MOL);
    }
    gemm_f32_k<false, false, false, true><<<g2d(N_MOLS, H), blk, 0, stream>>>(
        QSTARN, 2 * H, node_cond_W, H, nullptr, node_cond_b, MOL, H, N_MOLS, H, 2 * H);

    // 6. NN attention over steps
    gemm_f32_k<false, false, false, false><<<g2d(N_MOLS, H), blk, 0, stream>>>(
        MOL, H, W_nn0, H, nullptr, nullptr, PP, H, N_MOLS, H, H);
    gemm_f32_k<false, false, false, false><<<g2d(N_MOLS, H), blk, 0, stream>>>(
        MOL, H, W_nn0 + (size_t)H * H, H, nullptr, nullptr, QQ, H, N_MOLS, H, H);
    gemm_f32_k<false, false, false, true><<<g2d(N_MOLS, H), blk, 0, stream>>>(
        MOL, H, W_nn0s, H, nullptr, b_nn0s, SO, H, N_MOLS, H, H);
    build_x_k<<<(B_RXN * 16 * H) / 256, blk, 0, stream>>>(PP, QQ, SO, b_nn0, XBUF);
    gemm_f32_k<false, false, false, true><<<g2d(N_MOLS, H), blk, 0, stream>>>(
        XBUF, S_STEPS * H, W_nn1, H, nullptr, b_nn1, STEPS, H, N_MOLS, H, S_STEPS * H);

    // 7. graph Set2Set over [512, 4, 256]
    zero_f32_k<<<(524288 + 255) / 256, blk, 0, stream>>>(HG, 524288);    // HG,CG,QSTARG
    for (int it = 0; it < N_ITERS; ++it) {
        gemm_f32_k<true, false, false, false><<<g2d(B_RXN, 4 * H), blk, 0, stream>>>(
            QSTARG, 2 * H, lstm_g_Wih, 2 * H, nullptr, nullptr, GATESG, 4 * H, B_RXN, 4 * H, 2 * H);
        gemm_f32_k<true, false, true, true><<<g2d(B_RXN, 4 * H), blk, 0, stream>>>(
            HG, H, lstm_g_Whh, H, GATESG, lstm_g_b, GATESG, 4 * H, B_RXN, 4 * H, H);
        lstm_pw_k<<<(B_RXN * H) / 256, blk, 0, stream>>>(GATESG, HG, CG, B_RXN);
        s2s_attn_k<<<B_RXN, blk, 0, stream>>>(STEPS, HG, QSTARG, S_STEPS);
    }

    // 8. out
    gemm_f32_k<false, false, false, true><<<g2d(B_RXN, H), blk, 0, stream>>>(
        QSTARG, 2 * H, graph_cond_W, H, nullptr, graph_cond_b, out, H, B_RXN, H, 2 * H);
}

// Round 4
// 1095.717 us; speedup vs baseline: 1.9636x; 1.3816x over previous
//
#include <hip/hip_runtime.h>
#include <math.h>

// ---------------- problem constants ----------------
#define H 256
#define S_STEPS 4
#define B_RXN 512
#define N_MOLS 2048          // B*S
#define ATOMS_PER_MOL 32
#define N_ATOMS 65536        // N_MOLS*32
#define N_BONDS 131072
#define NBP1 131073          // N_BONDS+1
#define MAX_NB 6
#define ATOM_FDIM 133
#define BOND_FDIM 147
#define DEPTH 3
#define N_ITERS 3

typedef unsigned short bf16u;
typedef __attribute__((ext_vector_type(8))) short short8v;  // 8 bf16 = 4 VGPR
typedef __attribute__((ext_vector_type(4))) float f32x4;

__device__ __forceinline__ float b2f(bf16u u) {
    union { unsigned int i; float f; } c; c.i = ((unsigned int)u) << 16; return c.f;
}
__device__ __forceinline__ bf16u f2b(float f) {
    union { float f; unsigned int i; } c; c.f = f;
    unsigned int i = c.i;
    return (bf16u)((i + 0x7FFFu + ((i >> 16) & 1u)) >> 16);   // RNE
}

// ================= MFMA bf16 GEMM (bond/atom phase): C[M,256] = epi(A[M,K] @ B[K,256]) =====
// MODE 0 (WI):   A = f_bonds f32 [M,147] (KP=160);      epi: outb=bf16(acc), outb2=bf16(relu(acc))
// MODE 1 (MSG):  A = amsg[b2a[r]] - msg[b2revb[r]] bf16 (KP=256); epi: relu(acc+inp), row0=0 -> outb
// MODE 2 (ATOM): A = [f_atoms f32 133 | pad | amsg bf16 256] (KP=416); epi: relu(acc+bias) -> outf
template<int MODE>
__global__ __launch_bounds__(256) void mfma_gemm_k(
    const float* __restrict__ Af32,
    const bf16u* __restrict__ amsg,
    const bf16u* __restrict__ msgp,
    const bf16u* __restrict__ inp,
    const bf16u* __restrict__ WT,     // [256][KP] bf16 (pre-transposed, padded)
    const float* __restrict__ bias,
    const int* __restrict__ b2a,
    const int* __restrict__ b2revb,
    float* __restrict__ outf,
    bf16u* __restrict__ outb,
    bf16u* __restrict__ outb2,
    int M)
{
    constexpr int KP = (MODE == 0) ? 160 : ((MODE == 1) ? 256 : 416);
    __shared__ bf16u As[64][40];    // row-major [m][k], +8 pad
    __shared__ bf16u Bs[256][40];   // [n][k] (B transposed), +8 pad

    const int tid = threadIdx.x;
    const int lane = tid & 63, w = tid >> 6;
    const int m0 = blockIdx.x * 64;
    const int ar = tid >> 2, ac8 = (tid & 3) * 8;
    const int arow = m0 + ar;
    const bool rok = arow < M;
    size_t o1 = 0, o2 = 0;
    if (MODE == 1 && rok) {
        o1 = (size_t)b2a[arow] * H;
        o2 = (size_t)b2revb[arow] * H;
    }
    const int lr = lane & 15, lk = (lane >> 4) * 8;

    f32x4 acc[4][4];
    const f32x4 zf = {0.f, 0.f, 0.f, 0.f};
    #pragma unroll
    for (int i = 0; i < 4; ++i)
        #pragma unroll
        for (int j = 0; j < 4; ++j) acc[i][j] = zf;

    for (int k0 = 0; k0 < KP; k0 += 32) {
        ushort4 s0, s1;
        if (MODE == 1) {
            if (rok) {
                ushort4 ua0 = *(const ushort4*)(amsg + o1 + k0 + ac8);
                ushort4 ua1 = *(const ushort4*)(amsg + o1 + k0 + ac8 + 4);
                ushort4 ub0 = *(const ushort4*)(msgp + o2 + k0 + ac8);
                ushort4 ub1 = *(const ushort4*)(msgp + o2 + k0 + ac8 + 4);
                s0.x = f2b(b2f(ua0.x) - b2f(ub0.x)); s0.y = f2b(b2f(ua0.y) - b2f(ub0.y));
                s0.z = f2b(b2f(ua0.z) - b2f(ub0.z)); s0.w = f2b(b2f(ua0.w) - b2f(ub0.w));
                s1.x = f2b(b2f(ua1.x) - b2f(ub1.x)); s1.y = f2b(b2f(ua1.y) - b2f(ub1.y));
                s1.z = f2b(b2f(ua1.z) - b2f(ub1.z)); s1.w = f2b(b2f(ua1.w) - b2f(ub1.w));
            } else {
                s0 = make_ushort4(0, 0, 0, 0); s1 = make_ushort4(0, 0, 0, 0);
            }
        } else {
            float v[8];
            #pragma unroll
            for (int j = 0; j < 8; ++j) {
                int kk = k0 + ac8 + j;
                float x = 0.f;
                if (rok) {
                    if (MODE == 0) {
                        if (kk < BOND_FDIM) x = Af32[(size_t)arow * BOND_FDIM + kk];
                    } else {
                        if (kk < ATOM_FDIM) x = Af32[(size_t)arow * ATOM_FDIM + kk];
                        else if (kk >= 160) x = b2f(amsg[(size_t)arow * H + (kk - 160)]);
                    }
                }
                v[j] = x;
            }
            s0.x = f2b(v[0]); s0.y = f2b(v[1]); s0.z = f2b(v[2]); s0.w = f2b(v[3]);
            s1.x = f2b(v[4]); s1.y = f2b(v[5]); s1.z = f2b(v[6]); s1.w = f2b(v[7]);
        }
        *(ushort4*)&As[ar][ac8] = s0;
        *(ushort4*)&As[ar][ac8 + 4] = s1;

        {
            const bf16u* bp = WT + (size_t)tid * KP + k0;
            uint4 q0 = *(const uint4*)(bp);
            uint4 q1 = *(const uint4*)(bp + 8);
            uint4 q2 = *(const uint4*)(bp + 16);
            uint4 q3 = *(const uint4*)(bp + 24);
            *(uint4*)&Bs[tid][0]  = q0;
            *(uint4*)&Bs[tid][8]  = q1;
            *(uint4*)&Bs[tid][16] = q2;
            *(uint4*)&Bs[tid][24] = q3;
        }
        __syncthreads();

        short8v a[4], b[4];
        #pragma unroll
        for (int mf = 0; mf < 4; ++mf)
            a[mf] = *(const short8v*)&As[mf * 16 + lr][lk];
        #pragma unroll
        for (int nf = 0; nf < 4; ++nf)
            b[nf] = *(const short8v*)&Bs[w * 64 + nf * 16 + lr][lk];
        #pragma unroll
        for (int mf = 0; mf < 4; ++mf)
            #pragma unroll
            for (int nf = 0; nf < 4; ++nf)
                acc[mf][nf] = __builtin_amdgcn_mfma_f32_16x16x32_bf16(
                    a[mf], b[nf], acc[mf][nf], 0, 0, 0);
        __syncthreads();
    }

    const int rbase = (lane >> 4) * 4;
    #pragma unroll
    for (int mf = 0; mf < 4; ++mf) {
        #pragma unroll
        for (int nf = 0; nf < 4; ++nf) {
            const int col = w * 64 + nf * 16 + lr;
            #pragma unroll
            for (int r = 0; r < 4; ++r) {
                const int row = m0 + mf * 16 + rbase + r;
                if (row >= M) continue;
                float v = acc[mf][nf][r];
                const size_t off = (size_t)row * H + col;
                if (MODE == 0) {
                    outb[off] = f2b(v);
                    outb2[off] = f2b(fmaxf(v, 0.f));
                } else if (MODE == 1) {
                    v += b2f(inp[off]);
                    v = fmaxf(v, 0.f);
                    outb[off] = (row == 0) ? (bf16u)0 : f2b(v);
                } else {
                    v += bias[col];
                    v = fmaxf(v, 0.f);
                    outf[off] = v;
                }
            }
        }
    }
}

// ================= generic MFMA linear (mid phase): C[M,N] = A[M,K] @ WT^T + bias =========
// A is f32 (staged to bf16); dual-A fused-K: k < KA1 from A1, else A2 (pass A1 twice if unused).
// WT [N][K] bf16 pre-transposed. C f32 [M,N]. M % 64 == 0, N % 256 == 0, K % 32 == 0.
// grid = (M/64, N/256), 256 threads.
template<bool BIAS>
__global__ __launch_bounds__(256) void mfma_lin_k(
    const float* __restrict__ A1, int lda1, int KA1,
    const float* __restrict__ A2, int lda2,
    const bf16u* __restrict__ WT,
    const float* __restrict__ bias,
    float* __restrict__ C, int N, int K)
{
    __shared__ bf16u As[64][40];
    __shared__ bf16u Bs[256][40];
    const int tid = threadIdx.x;
    const int lane = tid & 63, w = tid >> 6;
    const int m0 = blockIdx.x * 64;
    const int col0 = blockIdx.y * 256;
    const int ar = tid >> 2, ac8 = (tid & 3) * 8;
    const int arow = m0 + ar;
    const int lr = lane & 15, lk = (lane >> 4) * 8;

    f32x4 acc[4][4];
    const f32x4 zf = {0.f, 0.f, 0.f, 0.f};
    #pragma unroll
    for (int i = 0; i < 4; ++i)
        #pragma unroll
        for (int j = 0; j < 4; ++j) acc[i][j] = zf;

    for (int k0 = 0; k0 < K; k0 += 32) {
        float v[8];
        #pragma unroll
        for (int j = 0; j < 8; ++j) {
            int kk = k0 + ac8 + j;
            v[j] = (kk < KA1) ? A1[(size_t)arow * lda1 + kk]
                              : A2[(size_t)arow * lda2 + (kk - KA1)];
        }
        ushort4 s0, s1;
        s0.x = f2b(v[0]); s0.y = f2b(v[1]); s0.z = f2b(v[2]); s0.w = f2b(v[3]);
        s1.x = f2b(v[4]); s1.y = f2b(v[5]); s1.z = f2b(v[6]); s1.w = f2b(v[7]);
        *(ushort4*)&As[ar][ac8] = s0;
        *(ushort4*)&As[ar][ac8 + 4] = s1;

        {
            const bf16u* bp = WT + (size_t)(col0 + tid) * K + k0;
            uint4 q0 = *(const uint4*)(bp);
            uint4 q1 = *(const uint4*)(bp + 8);
            uint4 q2 = *(const uint4*)(bp + 16);
            uint4 q3 = *(const uint4*)(bp + 24);
            *(uint4*)&Bs[tid][0]  = q0;
            *(uint4*)&Bs[tid][8]  = q1;
            *(uint4*)&Bs[tid][16] = q2;
            *(uint4*)&Bs[tid][24] = q3;
        }
        __syncthreads();

        short8v a[4], b[4];
        #pragma unroll
        for (int mf = 0; mf < 4; ++mf)
            a[mf] = *(const short8v*)&As[mf * 16 + lr][lk];
        #pragma unroll
        for (int nf = 0; nf < 4; ++nf)
            b[nf] = *(const short8v*)&Bs[w * 64 + nf * 16 + lr][lk];
        #pragma unroll
        for (int mf = 0; mf < 4; ++mf)
            #pragma unroll
            for (int nf = 0; nf < 4; ++nf)
                acc[mf][nf] = __builtin_amdgcn_mfma_f32_16x16x32_bf16(
                    a[mf], b[nf], acc[mf][nf], 0, 0, 0);
        __syncthreads();
    }

    const int rbase = (lane >> 4) * 4;
    #pragma unroll
    for (int mf = 0; mf < 4; ++mf) {
        #pragma unroll
        for (int nf = 0; nf < 4; ++nf) {
            const int col = col0 + w * 64 + nf * 16 + lr;
            #pragma unroll
            for (int r = 0; r < 4; ++r) {
                const int row = m0 + mf * 16 + rbase + r;
                float v = acc[mf][nf][r];
                if (BIAS) v += bias[col];
                C[(size_t)row * N + col] = v;
            }
        }
    }
}

// ---------------- weight prep kernels ----------------
// WT[n][k] = bf16(W[k][n]) for W [K,256] row-major
__global__ __launch_bounds__(256) void prep_wt_k(const float* __restrict__ W,
                                                 bf16u* __restrict__ WT, int K, int KP)
{
    int idx = blockIdx.x * 256 + threadIdx.x;
    if (idx >= 256 * KP) return;
    int n = idx / KP, k = idx - n * KP;
    WT[idx] = (k < K) ? f2b(W[(size_t)k * H + n]) : (bf16u)0;
}

// W_o variant: k<133 -> Wo[k]; [133,160) -> 0; k>=160 -> Wo[133+k-160]
__global__ __launch_bounds__(256) void prep_wto_k(const float* __restrict__ Wo,
                                                  bf16u* __restrict__ WT)
{
    int idx = blockIdx.x * 256 + threadIdx.x;
    if (idx >= 256 * 416) return;
    int n = idx / 416, k = idx - n * 416;
    float v = 0.f;
    if (k < ATOM_FDIM) v = Wo[(size_t)k * H + n];
    else if (k >= 160) v = Wo[(size_t)(ATOM_FDIM + k - 160) * H + n];
    WT[idx] = f2b(v);
}

// generic transpose-convert: W [K, 256] -> WT [256][K]
__global__ __launch_bounds__(256) void prep_wt_t_k(const float* __restrict__ W,
                                                   bf16u* __restrict__ WT, int K)
{
    int idx = blockIdx.x * 256 + threadIdx.x;
    if (idx >= 256 * K) return;
    int n = idx / K, k = idx - n * K;
    WT[idx] = f2b(W[(size_t)k * 256 + n]);
}

// LSTM gates: WT [1024][768] = [Wih[n] | Whh[n]] bf16 (already [n][k] layout)
__global__ __launch_bounds__(256) void prep_wt_gates_k(const float* __restrict__ Wih,
                                                       const float* __restrict__ Whh,
                                                       bf16u* __restrict__ WT)
{
    int idx = blockIdx.x * 256 + threadIdx.x;
    if (idx >= 1024 * 768) return;
    int n = idx / 768, k = idx - n * 768;
    WT[idx] = f2b(k < 512 ? Wih[(size_t)n * 512 + k] : Whh[(size_t)n * 256 + (k - 512)]);
}

// ---------------- small kernels ----------------
__global__ __launch_bounds__(256) void gather6_bf16_k(const bf16u* __restrict__ msg,
                                                      const int* __restrict__ a2b,
                                                      bf16u* __restrict__ outb)
{
    int idx = blockIdx.x * 256 + threadIdx.x;
    if (idx >= N_ATOMS * (H / 8)) return;
    int na = idx >> 5, c = idx & 31;
    const int* nb = a2b + (size_t)na * MAX_NB;
    float s[8] = {0.f, 0.f, 0.f, 0.f, 0.f, 0.f, 0.f, 0.f};
    #pragma unroll
    for (int j = 0; j < MAX_NB; ++j) {
        const bf16u* rowp = msg + (size_t)nb[j] * H + c * 8;
        ushort4 u0 = *(const ushort4*)rowp;
        ushort4 u1 = *(const ushort4*)(rowp + 4);
        s[0] += b2f(u0.x); s[1] += b2f(u0.y); s[2] += b2f(u0.z); s[3] += b2f(u0.w);
        s[4] += b2f(u1.x); s[5] += b2f(u1.y); s[6] += b2f(u1.z); s[7] += b2f(u1.w);
    }
    bf16u* op = outb + (size_t)na * H + c * 8;
    ushort4 r0, r1;
    r0.x = f2b(s[0]); r0.y = f2b(s[1]); r0.z = f2b(s[2]); r0.w = f2b(s[3]);
    r1.x = f2b(s[4]); r1.y = f2b(s[5]); r1.z = f2b(s[6]); r1.w = f2b(s[7]);
    *(ushort4*)op = r0;
    *(ushort4*)(op + 4) = r1;
}

__global__ __launch_bounds__(256) void zero_f32_k(float* __restrict__ p, int n)
{
    int idx = blockIdx.x * 256 + threadIdx.x;
    if (idx < n) p[idx] = 0.f;
}

__device__ __forceinline__ float sigm(float x) { return 1.f / (1.f + expf(-x)); }

__global__ __launch_bounds__(256) void lstm_pw_k(const float* __restrict__ gates,
                                                 float* __restrict__ h,
                                                 float* __restrict__ c, int M)
{
    int idx = blockIdx.x * 256 + threadIdx.x;
    if (idx >= M * H) return;
    int m = idx >> 8, d = idx & 255;
    const float* g = gates + (size_t)m * (4 * H);
    float ig = sigm(g[d]);
    float fg = sigm(g[H + d]);
    float gg = tanhf(g[2 * H + d]);
    float og = sigm(g[3 * H + d]);
    float cn = fg * c[idx] + ig * gg;
    c[idx] = cn;
    h[idx] = og * tanhf(cn);
}

__global__ __launch_bounds__(256) void s2s_attn_k(const float* __restrict__ feat,
                                                  const float* __restrict__ h,
                                                  float* __restrict__ q_star, int Nn)
{
    int m = blockIdx.x;
    int t = threadIdx.x;
    int lane = t & 63, wave = t >> 6;
    __shared__ float sc[32];
    const float* f = feat + (size_t)m * Nn * H;
    const float* hm = h + (size_t)m * H;
    for (int n = wave; n < Nn; n += 4) {
        const float* fr = f + (size_t)n * H;
        float p = 0.f;
        #pragma unroll
        for (int u = 0; u < 4; ++u) p += fr[lane * 4 + u] * hm[lane * 4 + u];
        #pragma unroll
        for (int o = 32; o >= 1; o >>= 1) p += __shfl_xor(p, o);
        if (lane == 0) sc[n] = p;
    }
    __syncthreads();
    float mx = -1e30f;
    for (int n = 0; n < Nn; ++n) mx = fmaxf(mx, sc[n]);
    float ssum = 0.f, r = 0.f;
    for (int n = 0; n < Nn; ++n) {
        float a = expf(sc[n] - mx);
        ssum += a;
        r += a * f[(size_t)n * H + t];
    }
    r /= ssum;
    q_star[(size_t)m * (2 * H) + t] = hm[t];
    q_star[(size_t)m * (2 * H) + H + t] = r;
}

__global__ __launch_bounds__(256) void build_x_k(const float* __restrict__ P,
                                                 const float* __restrict__ Q,
                                                 const float* __restrict__ SO,
                                                 const float* __restrict__ b0,
                                                 float* __restrict__ X)
{
    int idx = blockIdx.x * 256 + threadIdx.x;
    if (idx >= B_RXN * S_STEPS * S_STEPS * H) return;
    int d  = idx & 255;
    int s2 = (idx >> 8) & 3;
    int s1 = (idx >> 10) & 3;
    int b  = idx >> 12;
    float v;
    if (s1 == s2) v = SO[((size_t)b * S_STEPS + s1) * H + d];
    else v = P[((size_t)b * S_STEPS + s1) * H + d] + Q[((size_t)b * S_STEPS + s2) * H + d] + b0[d];
    X[idx] = v;
}

// ---------------- launch ----------------
extern "C" void kernel_launch(void* const* d_in, const int* in_sizes, int n_in,
                              void* d_out, int out_size, void* d_ws, size_t ws_size,
                              hipStream_t stream)
{
    const float* f_atoms   = (const float*)d_in[0];
    const float* f_bonds   = (const float*)d_in[1];
    const int*   a2b       = (const int*)d_in[2];
    const int*   b2a       = (const int*)d_in[3];
    const int*   b2revb    = (const int*)d_in[4];
    const float* W_i       = (const float*)d_in[5];
    const float* W_h       = (const float*)d_in[6];
    const float* W_o       = (const float*)d_in[7];
    const float* b_o       = (const float*)d_in[8];
    const float* W_nn0     = (const float*)d_in[9];
    const float* b_nn0     = (const float*)d_in[10];
    const float* W_nn0s    = (const float*)d_in[11];
    const float* b_nn0s    = (const float*)d_in[12];
    const float* W_nn1     = (const float*)d_in[13];
    const float* b_nn1     = (const float*)d_in[14];
    const float* lstm_n_Wih = (const float*)d_in[15];
    const float* lstm_n_Whh = (const float*)d_in[16];
    const float* lstm_n_b   = (const float*)d_in[17];
    const float* node_cond_W = (const float*)d_in[18];
    const float* node_cond_b = (const float*)d_in[19];
    const float* lstm_g_Wih = (const float*)d_in[20];
    const float* lstm_g_Whh = (const float*)d_in[21];
    const float* lstm_g_b   = (const float*)d_in[22];
    const float* graph_cond_W = (const float*)d_in[23];
    const float* graph_cond_b = (const float*)d_in[24];
    float* out = (float*)d_out;

    // ---- workspace layout ----
    const size_t SZB = (size_t)NBP1 * H * sizeof(bf16u);    // 67,109,376 B
    char* base = (char*)d_ws;
    bf16u* INP  = (bf16u*)(base);
    bf16u* MSGA = (bf16u*)(base + SZB);
    bf16u* MSGB = (bf16u*)(base + 2 * SZB);
    bf16u* AMSG = (bf16u*)(base + 3 * SZB);                 // [N_ATOMS,H] bf16 (33,554,432 B)
    bf16u* WT_I = (bf16u*)(base + 3 * SZB + 33554432);      // [256][160]
    bf16u* WT_H = (bf16u*)(base + 3 * SZB + 33636352);      // [256][256]
    bf16u* WT_O = (bf16u*)(base + 3 * SZB + 33767424);      // [256][416]
    // aliases (regions dead at time of use):
    float* ATOMH = (float*)(base);                          // [N_ATOMS,H] f32, alias INP
    float* SMALL = (float*)(base + SZB);                    // f32 scratch, alias MSGA (67 MB)
    float* GATES  = SMALL;                                  // [2048,1024]
    float* HN     = SMALL + 2097152;                        // [2048,256]
    float* CN     = SMALL + 2621440;                        // [2048,256]
    float* QSTARN = SMALL + 3145728;                        // [2048,512]
    float* MOL    = SMALL + 4194304;                        // [2048,256]
    float* PP     = SMALL + 4718592;                        // [2048,256]
    float* QQ     = SMALL + 5242880;                        // [2048,256]
    float* SO     = SMALL + 5767168;                        // [2048,256]
    float* XBUF   = SMALL + 6291456;                        // [8192,256]
    float* STEPS  = SMALL + 8388608;                        // [2048,256]
    float* HG     = SMALL + 8912896;                        // [512,256]
    float* CG     = SMALL + 9043968;                        // [512,256]
    float* QSTARG = SMALL + 9175040;                        // [512,512]
    float* GATESG = SMALL + 9437184;                        // [512,1024]
    // mid-phase weights: alias MSGA region at +40 MB (written only after MSGA is dead)
    char* sm2 = base + SZB + 41943040;
    bf16u* WTG_N = (bf16u*)(sm2);                 // [1024][768] = 1,572,864 B
    bf16u* WTG_G = (bf16u*)(sm2 + 1572864);       // [1024][768]
    bf16u* WT_NC = (bf16u*)(sm2 + 3145728);       // [256][512]  =   262,144
    bf16u* WT_P  = (bf16u*)(sm2 + 3407872);       // [256][256]
    bf16u* WT_Q  = (bf16u*)(sm2 + 3538944);       // [256][256]
    bf16u* WT_S  = (bf16u*)(sm2 + 3670016);       // [256][256]
    bf16u* WT_N1 = (bf16u*)(sm2 + 3801088);       // [256][1024] =   524,288
    bf16u* WT_GC = (bf16u*)(sm2 + 4325376);       // [256][512]  -> ends +4,587,520 < 67 MB

    dim3 blk(256);
    const int MB_BOND = (NBP1 + 63) / 64;     // 2049
    const int MB_ATOM = N_ATOMS / 64;         // 1024

    // 0. bond/atom weight prep
    prep_wt_k<<<(256 * 160 + 255) / 256, blk, 0, stream>>>(W_i, WT_I, BOND_FDIM, 160);
    prep_wt_k<<<(256 * 256 + 255) / 256, blk, 0, stream>>>(W_h, WT_H, H, 256);
    prep_wto_k<<<(256 * 416 + 255) / 256, blk, 0, stream>>>(W_o, WT_O);

    // 1. inp = f_bonds @ W_i -> INP (bf16) ; MSGA = relu(inp) (fused)
    mfma_gemm_k<0><<<MB_BOND, blk, 0, stream>>>(
        f_bonds, nullptr, nullptr, nullptr, WT_I, nullptr, nullptr, nullptr,
        nullptr, INP, MSGA, NBP1);

    // 2. depth loop
    bf16u* cur = MSGA; bf16u* nxt = MSGB;
    for (int d = 0; d < DEPTH - 1; ++d) {
        gather6_bf16_k<<<(N_ATOMS * (H / 8) + 255) / 256, blk, 0, stream>>>(cur, a2b, AMSG);
        mfma_gemm_k<1><<<MB_BOND, blk, 0, stream>>>(
            nullptr, AMSG, cur, INP, WT_H, nullptr, b2a, b2revb,
            nullptr, nxt, nullptr, NBP1);
        bf16u* t = cur; cur = nxt; nxt = t;
    }

    // 3. nei = gather-sum(final message)  (cur == MSGA)
    gather6_bf16_k<<<(N_ATOMS * (H / 8) + 255) / 256, blk, 0, stream>>>(cur, a2b, AMSG);

    // 3b. mid-phase weight prep (MSGA region now dead)
    prep_wt_gates_k<<<(1024 * 768 + 255) / 256, blk, 0, stream>>>(lstm_n_Wih, lstm_n_Whh, WTG_N);
    prep_wt_gates_k<<<(1024 * 768 + 255) / 256, blk, 0, stream>>>(lstm_g_Wih, lstm_g_Whh, WTG_G);
    prep_wt_t_k<<<(256 * 512 + 255) / 256, blk, 0, stream>>>(node_cond_W, WT_NC, 512);
    prep_wt_t_k<<<(256 * 256 + 255) / 256, blk, 0, stream>>>(W_nn0, WT_P, 256);
    prep_wt_t_k<<<(256 * 256 + 255) / 256, blk, 0, stream>>>(W_nn0 + 256 * 256, WT_Q, 256);
    prep_wt_t_k<<<(256 * 256 + 255) / 256, blk, 0, stream>>>(W_nn0s, WT_S, 256);
    prep_wt_t_k<<<(256 * 1024 + 255) / 256, blk, 0, stream>>>(W_nn1, WT_N1, 1024);
    prep_wt_t_k<<<(256 * 512 + 255) / 256, blk, 0, stream>>>(graph_cond_W, WT_GC, 512);

    // 4. atom_h = relu([f_atoms, nei] @ W_o + b_o) -> ATOMH f32 (aliases dead INP)
    mfma_gemm_k<2><<<MB_ATOM, blk, 0, stream>>>(
        f_atoms, AMSG, nullptr, nullptr, WT_O, b_o, nullptr, nullptr,
        ATOMH, nullptr, nullptr, N_ATOMS);

    // 5. node Set2Set over [2048, 32, 256]
    zero_f32_k<<<(2097152 + 255) / 256, blk, 0, stream>>>(HN, 2097152);  // HN,CN,QSTARN
    for (int it = 0; it < N_ITERS; ++it) {
        mfma_lin_k<true><<<dim3(N_MOLS / 64, 4), blk, 0, stream>>>(
            QSTARN, 2 * H, 2 * H, HN, H, WTG_N, lstm_n_b, GATES, 4 * H, 3 * H);
        lstm_pw_k<<<(N_MOLS * H) / 256, blk, 0, stream>>>(GATES, HN, CN, N_MOLS);
        s2s_attn_k<<<N_MOLS, blk, 0, stream>>>(ATOMH, HN, QSTARN, ATOMS_PER_MOL);
    }
    mfma_lin_k<true><<<dim3(N_MOLS / 64, 1), blk, 0, stream>>>(
        QSTARN, 2 * H, 2 * H, QSTARN, 2 * H, WT_NC, node_cond_b, MOL, H, 2 * H);

    // 6. NN attention over steps
    mfma_lin_k<false><<<dim3(N_MOLS / 64, 1), blk, 0, stream>>>(
        MOL, H, H, MOL, H, WT_P, nullptr, PP, H, H);
    mfma_lin_k<false><<<dim3(N_MOLS / 64, 1), blk, 0, stream>>>(
        MOL, H, H, MOL, H, WT_Q, nullptr, QQ, H, H);
    mfma_lin_k<true><<<dim3(N_MOLS / 64, 1), blk, 0, stream>>>(
        MOL, H, H, MOL, H, WT_S, b_nn0s, SO, H, H);
    build_x_k<<<(B_RXN * 16 * H) / 256, blk, 0, stream>>>(PP, QQ, SO, b_nn0, XBUF);
    mfma_lin_k<true><<<dim3(N_MOLS / 64, 1), blk, 0, stream>>>(
        XBUF, S_STEPS * H, S_STEPS * H, XBUF, S_STEPS * H, WT_N1, b_nn1, STEPS, H, S_STEPS * H);

    // 7. graph Set2Set over [512, 4, 256]
    zero_f32_k<<<(524288 + 255) / 256, blk, 0, stream>>>(HG, 524288);    // HG,CG,QSTARG
    for (int it = 0; it < N_ITERS; ++it) {
        mfma_lin_k<true><<<dim3(B_RXN / 64, 4), blk, 0, stream>>>(
            QSTARG, 2 * H, 2 * H, HG, H, WTG_G, lstm_g_b, GATESG, 4 * H, 3 * H);
        lstm_pw_k<<<(B_RXN * H) / 256, blk, 0, stream>>>(GATESG, HG, CG, B_RXN);
        s2s_attn_k<<<B_RXN, blk, 0, stream>>>(STEPS, HG, QSTARG, S_STEPS);
    }

    // 8. out
    mfma_lin_k<true><<<dim3(B_RXN / 64, 1), blk, 0, stream>>>(
        QSTARG, 2 * H, 2 * H, QSTARG, 2 * H, WT_GC, graph_cond_b, out, H, 2 * H);
}